// Round 7
// baseline (689.724 us; speedup 1.0000x reference)
//
#include <hip/hip_runtime.h>
#include <math.h>

typedef __attribute__((ext_vector_type(8))) short bf16x8;
typedef __attribute__((ext_vector_type(4))) float f32x4;
typedef __attribute__((ext_vector_type(2))) float f32x2;
typedef __attribute__((ext_vector_type(4))) unsigned u32x4;

union B8 { bf16x8 v; unsigned u[4]; u32x4 q; };

__device__ __forceinline__ unsigned pk2(float lo, float hi) {
  unsigned r;
  asm("v_cvt_pk_bf16_f32 %0, %1, %2" : "=v"(r) : "v"(lo), "v"(hi));
  return r;
}
__device__ __forceinline__ f32x2 pkmul(f32x2 a, f32x2 b) {
  f32x2 r;
  asm("v_pk_mul_f32 %0, %1, %2" : "=v"(r) : "v"(a), "v"(b));
  return r;
}
__device__ __forceinline__ float rcpf(float x) { return __builtin_amdgcn_rcpf(x); }
__device__ __forceinline__ void ldsfence() { asm volatile("s_waitcnt lgkmcnt(0)" ::: "memory"); }

#define MFMA __builtin_amdgcn_mfma_f32_16x16x32_bf16

// ---------------- prep: Kopen pack [0..1023], symA [1024..1312], sumA2 [1313], k0sq [1320..1383]
__global__ void otflow_prep(const float* __restrict__ K0g,
                            const float* __restrict__ Ag,
                            float* __restrict__ ws) {
  __shared__ float Als[170];
  int tid = threadIdx.x;
  for (int idx = tid; idx < 1024; idx += 256) {
    int m = idx >> 4, d = idx & 15;
    ws[idx] = K0g[m * 17 + d];
  }
  if (tid < 170) Als[tid] = Ag[tid];
  if (tid < 64) {
    float s = 0.f;
    for (int d = 0; d < 16; ++d) { float v = K0g[tid * 17 + d]; s += v * v; }
    ws[1320 + tid] = s;
  }
  __syncthreads();
  for (int idx = tid; idx < 289; idx += 256) {
    int j = idx / 17, k2 = idx % 17;
    float s = 0.f;
#pragma unroll
    for (int r = 0; r < 10; ++r) s += Als[r * 17 + j] * Als[r * 17 + k2];
    ws[1024 + idx] = s;
  }
  __syncthreads();
  if (tid == 0) {
    float s = 0.f;
    for (int r = 0; r < 10; ++r)
      for (int j = 0; j < 16; ++j) { float v = Als[r * 17 + j]; s += v * v; }
    ws[1313] = s;
  }
}

// ---------------- main: 128 threads = 2 INDEPENDENT waves, each owns 8 particles.
// No barriers after init. Per-wave dataflow identical to verified R3 path.
__global__ __launch_bounds__(128, 3) void otflow_main(
    const float* __restrict__ xg, const float* __restrict__ wg,
    const float* __restrict__ bg, const float* __restrict__ K0g,
    const float* __restrict__ b0g, const float* __restrict__ K1g,
    const float* __restrict__ b1g, const int* __restrict__ ntg,
    const float* __restrict__ ws, float* __restrict__ out, int n) {
  __shared__ unsigned aK0lds[8 * 64 * 4];   // shared bf16 frags: h0..h3, l0..l3
  __shared__ unsigned Xu[2][8 * 36];        // packed bf16 pairs: u0 -> a -> rv
  __shared__ float csh[2][8 * 68];          // S-bounce -> c
  __shared__ float qsh[2][8 * 68];          // q
  __shared__ float gsh[2][8 * 20];          // grad rows
  __shared__ float tshv[2][8];              // per-particle t1
  __shared__ float b0s[64], tcs[64], b1s[64], wss[64], k0qs[64], scol[18];

  const int tid = threadIdx.x;
  const int wid = tid >> 6;
  const int lane = tid & 63;
  const int lr = lane & 15;
  const int lg = lane >> 4;
  const int p8 = lr & 7;
  const bool own = (lr < 8);

  if (wid == 0) {
    b0s[lane] = b0g[lane];
    tcs[lane] = K0g[lane * 17 + 16];
    b1s[lane] = b1g[lane];
    wss[lane] = wg[lane];
    k0qs[lane] = ws[1320 + lane];
    if (lane < 17) scol[lane] = ws[1024 + lane * 17 + 16];
    if (lane == 17) scol[17] = bg[16];
    // K0 hi/lo fragments (A-layout, k duplicated over lg-halves)
#pragma unroll
    for (int mi = 0; mi < 4; ++mi) {
      unsigned th[4], tl[4];
#pragma unroll
      for (int jj = 0; jj < 4; ++jj) {
        float e0 = K0g[(mi * 16 + lr) * 17 + (lg & 1) * 8 + jj * 2];
        float e1 = K0g[(mi * 16 + lr) * 17 + (lg & 1) * 8 + jj * 2 + 1];
        unsigned hh = pk2(e0, e1);
        th[jj] = hh;
        float l0 = e0 - __uint_as_float(hh << 16);
        float l1 = e1 - __uint_as_float(hh & 0xffff0000u);
        tl[jj] = pk2(l0, l1);
      }
      *(u32x4*)(aK0lds + (mi * 64 + lane) * 4) = (u32x4){th[0], th[1], th[2], th[3]};
      *(u32x4*)(aK0lds + ((4 + mi) * 64 + lane) * 4) = (u32x4){tl[0], tl[1], tl[2], tl[3]};
    }
  }

  const float sumA2 = ws[1313];

  // ---- per-wave const fragments (VGPR) ----
  B8 aK1[8];
#pragma unroll
  for (int mi = 0; mi < 4; ++mi)
#pragma unroll
    for (int kb = 0; kb < 2; ++kb) {
      const float* pp = K1g + (mi * 16 + lr) * 64 + kb * 32 + lg * 8;
      float4 q0 = *(const float4*)pp;
      float4 q1 = *(const float4*)(pp + 4);
      B8 t;
      t.u[0] = pk2(q0.x, q0.y); t.u[1] = pk2(q0.z, q0.w);
      t.u[2] = pk2(q1.x, q1.y); t.u[3] = pk2(q1.z, q1.w);
      aK1[mi * 2 + kb] = t;
    }
  B8 aK1T[8];
#pragma unroll
  for (int mi = 0; mi < 4; ++mi)
#pragma unroll
    for (int kb = 0; kb < 2; ++kb) {
      int ib = kb * 32 + lg * 8;
      int m = mi * 16 + lr;
      B8 tt;
#pragma unroll
      for (int jj = 0; jj < 4; ++jj)
        tt.u[jj] = pk2(K1g[(ib + jj * 2) * 64 + m], K1g[(ib + jj * 2 + 1) * 64 + m]);
      aK1T[mi * 2 + kb] = tt;
    }
  B8 aG0[3];                       // grad tile j=lr (0..15), K=96
  {
    int j = lr;
#pragma unroll
    for (int kb = 0; kb < 3; ++kb) {
      float e[8];
#pragma unroll
      for (int jj = 0; jj < 8; ++jj) {
        float v;
        if (kb < 2) v = K0g[(kb * 32 + lg * 8 + jj) * 17 + j];
        else {
          int kr = lg * 8 + jj;
          v = (kr < 17) ? ws[1024 + kr * 17 + j] : (kr == 17) ? bg[j] : 0.f;
        }
        e[jj] = v;
      }
      B8 t;
      t.u[0] = pk2(e[0], e[1]); t.u[1] = pk2(e[2], e[3]);
      t.u[2] = pk2(e[4], e[5]); t.u[3] = pk2(e[6], e[7]);
      aG0[kb] = t;
    }
  }
  f32x2 kop2[8];                   // Kopen[m][lr] pairs, m = kb*32+lg*8+2j..+1
#pragma unroll
  for (int kb = 0; kb < 2; ++kb)
#pragma unroll
    for (int j = 0; j < 4; ++j) {
      f32x2 t;
      t.x = ws[(kb * 32 + lg * 8 + 2 * j) * 16 + lr];
      t.y = ws[(kb * 32 + lg * 8 + 2 * j + 1) * 16 + lr];
      kop2[kb * 4 + j] = t;
    }

  __syncthreads();   // one-time: shared consts ready; waves independent hereafter

  float4 sc4 = *(const float4*)(scol + lg * 4);
  const float sc16 = scol[16], sc17 = scol[17];

  const int nt = *ntg;
  const float h = 1.0f / (float)nt;
  const int pbase = blockIdx.x * 16 + wid * 8;
  int pidx = pbase + p8; if (pidx >= n) pidx = n - 1;

  float xin[4], x0s[4], xac[4];
  {
    float4 xi = *(const float4*)(xg + (size_t)pidx * 16 + lg * 4);
    xin[0] = xi.x; xin[1] = xi.y; xin[2] = xi.z; xin[3] = xi.w;
#pragma unroll
    for (int r = 0; r < 4; ++r) { x0s[r] = xin[r]; xac[r] = xin[r]; }
  }
  float lacc = 0.f, vacc = 0.f, racc = 0.f;
  const f32x4 zz = {0.f, 0.f, 0.f, 0.f};

  unsigned* Xw = Xu[wid];
  float* cw = csh[wid];
  float* qw = qsh[wid];
  float* gw = gsh[wid];

  for (int kstep = 0; kstep < nt; ++kstep) {
    float t0 = (float)kstep * h;
#pragma unroll 1
    for (int st = 0; st < 4; ++st) {
      float tin = t0 + ((st == 0) ? 0.f : (st == 3) ? h : 0.5f * h);

      // ---- S-bounce + frag build (hi/lo exact opening; bf16-hi grad S)
      if (own) {
        float4 xv = {xin[0], xin[1], xin[2], xin[3]};
        *(float4*)(cw + p8 * 68 + lg * 4) = xv;
      }
      ldsfence();
      const float* sp = cw + p8 * 68;
      float4 s0 = *(const float4*)(sp + (lg & 1) * 8);
      float4 s1 = *(const float4*)(sp + (lg & 1) * 8 + 4);
      unsigned h0 = pk2(s0.x, s0.y), h1 = pk2(s0.z, s0.w);
      unsigned h2 = pk2(s1.x, s1.y), h3 = pk2(s1.z, s1.w);
      B8 sfO, sfG;
      if (lg < 2) {
        sfO.u[0] = h0; sfO.u[1] = h1; sfO.u[2] = h2; sfO.u[3] = h3;
        sfG.u[0] = h0; sfG.u[1] = h1; sfG.u[2] = h2; sfG.u[3] = h3;
      } else {
        float l0 = s0.x - __uint_as_float(h0 << 16);
        float l1 = s0.y - __uint_as_float(h0 & 0xffff0000u);
        float l2 = s0.z - __uint_as_float(h1 << 16);
        float l3 = s0.w - __uint_as_float(h1 & 0xffff0000u);
        float l4 = s1.x - __uint_as_float(h2 << 16);
        float l5 = s1.y - __uint_as_float(h2 & 0xffff0000u);
        float l6 = s1.z - __uint_as_float(h3 << 16);
        float l7 = s1.w - __uint_as_float(h3 & 0xffff0000u);
        sfO.u[0] = pk2(l0, l1); sfO.u[1] = pk2(l2, l3);
        sfO.u[2] = pk2(l4, l5); sfO.u[3] = pk2(l6, l7);
        if (lg == 2) { sfG.u[0] = pk2(tin, 1.f); sfG.u[1] = 0; sfG.u[2] = 0; sfG.u[3] = 0; }
        else { sfG.u[0] = 0; sfG.u[1] = 0; sfG.u[2] = 0; sfG.u[3] = 0; }
      }

      // ---- opening (K0 frags from shared LDS)
      B8 k0f[8];
#pragma unroll
      for (int f = 0; f < 8; ++f) k0f[f].q = *(const u32x4*)(aK0lds + (f * 64 + lane) * 4);
      f32x4 oA[4];
#pragma unroll
      for (int mi = 0; mi < 4; ++mi) {
        oA[mi] = MFMA(k0f[mi].v, sfO.v, zz, 0, 0, 0);
        oA[mi] = MFMA(k0f[4 + mi].v, sfO.v, oA[mi], 0, 0, 0);
      }
#pragma unroll
      for (int mi = 0; mi < 4; ++mi) {
        float4 b0v = *(const float4*)(b0s + mi * 16 + lg * 4);
        float4 tcv = *(const float4*)(tcs + mi * 16 + lg * 4);
        float u0v[4], cv[4];
#pragma unroll
        for (int r = 0; r < 4; ++r) {
          float ov = oA[mi][r] + fmaf(tin, ((const float*)&tcv)[r], ((const float*)&b0v)[r]);
          float e = __expf(-2.f * fabsf(ov));
          float rp = rcpf(1.f + e);
          cv[r] = __builtin_copysignf((1.f - e) * rp, ov);
          u0v[r] = fabsf(ov) + __logf(1.f + e);
        }
        unsigned ua = pk2(u0v[0], u0v[1]), ub = pk2(u0v[2], u0v[3]);
        if (own) {
          *(uint2*)(Xw + p8 * 36 + mi * 8 + lg * 2) = make_uint2(ua, ub);
          float4 cf = {cv[0], cv[1], cv[2], cv[3]};
          *(float4*)(cw + p8 * 68 + mi * 16 + lg * 4) = cf;
        }
      }
      ldsfence();

      // ---- feat1 = K1 @ u0 (packed-bf16 direct read)
      B8 uf0, uf1;
      uf0.q = *(const u32x4*)(Xw + p8 * 36 + lg * 4);
      uf1.q = *(const u32x4*)(Xw + p8 * 36 + 16 + lg * 4);
      f32x4 fA[4];
#pragma unroll
      for (int mi = 0; mi < 4; ++mi) {
        fA[mi] = MFMA(aK1[mi * 2].v, uf0.v, zz, 0, 0, 0);
        fA[mi] = MFMA(aK1[mi * 2 + 1].v, uf1.v, fA[mi], 0, 0, 0);
      }
#pragma unroll
      for (int mi = 0; mi < 4; ++mi) {
        float4 b1v = *(const float4*)(b1s + mi * 16 + lg * 4);
        float4 wv = *(const float4*)(wss + mi * 16 + lg * 4);
        float av[4], qv[4];
#pragma unroll
        for (int r = 0; r < 4; ++r) {
          float fv = fA[mi][r] + ((const float*)&b1v)[r];
          float e = __expf(-2.f * fabsf(fv));
          float rp = rcpf(1.f + e);
          float tf = __builtin_copysignf((1.f - e) * rp, fv);
          float wr = ((const float*)&wv)[r];
          av[r] = tf * wr;
          qv[r] = (1.f - tf * tf) * wr;
        }
        unsigned pa = pk2(av[0], av[1]), pb = pk2(av[2], av[3]);
        if (own) {
          *(uint2*)(Xw + p8 * 36 + mi * 8 + lg * 2) = make_uint2(pa, pb);
          float4 qf = {qv[0], qv[1], qv[2], qv[3]};
          *(float4*)(qw + p8 * 68 + mi * 16 + lg * 4) = qf;
        }
      }
      ldsfence();

      // ---- z1 = K1^T @ a ; rv packed to Xu; trh + g16 partials in-reg
      B8 af0, af1;
      af0.q = *(const u32x4*)(Xw + p8 * 36 + lg * 4);
      af1.q = *(const u32x4*)(Xw + p8 * 36 + 16 + lg * 4);
      f32x4 zA[4];
#pragma unroll
      for (int mi = 0; mi < 4; ++mi) {
        zA[mi] = MFMA(aK1T[mi * 2].v, af0.v, zz, 0, 0, 0);
        zA[mi] = MFMA(aK1T[mi * 2 + 1].v, af1.v, zA[mi], 0, 0, 0);
      }
      float trh_l = 0.f, g16p = 0.f;
#pragma unroll
      for (int mi = 0; mi < 4; ++mi) {
        float4 wv = *(const float4*)(wss + mi * 16 + lg * 4);
        float4 kq = *(const float4*)(k0qs + mi * 16 + lg * 4);
        float4 tcv = *(const float4*)(tcs + mi * 16 + lg * 4);
        float4 cv4 = *(const float4*)(cw + p8 * 68 + mi * 16 + lg * 4);
        float rv[4];
#pragma unroll
        for (int r = 0; r < 4; ++r) {
          float c = ((const float*)&cv4)[r];
          float z1v = zA[mi][r] + ((const float*)&wv)[r];
          rv[r] = c * z1v;
          trh_l = fmaf((1.f - c * c) * z1v, ((const float*)&kq)[r], trh_l);
          g16p = fmaf(rv[r], ((const float*)&tcv)[r], g16p);
        }
        unsigned ra = pk2(rv[0], rv[1]), rb = pk2(rv[2], rv[3]);
        if (own) *(uint2*)(Xw + p8 * 36 + mi * 8 + lg * 2) = make_uint2(ra, rb);
      }
#pragma unroll
      for (int r = 0; r < 4; ++r) g16p = fmaf(xin[r], ((const float*)&sc4)[r], g16p);
      trh_l += __shfl_xor(trh_l, 16, 64);
      trh_l += __shfl_xor(trh_l, 32, 64);
      g16p += __shfl_xor(g16p, 16, 64);
      g16p += __shfl_xor(g16p, 32, 64);
      float g16 = g16p + fmaf(tin, sc16, sc17);
      ldsfence();

      // ---- KJ: 8 particles, full-wave butterfly t1 (R5-verified reduction)
#pragma unroll 2
      for (int p = 0; p < 8; ++p) {
        const float* cp = cw + p * 68;
        float4 ca = *(const float4*)(cp + lg * 8);
        float4 cb = *(const float4*)(cp + lg * 8 + 4);
        float4 cc = *(const float4*)(cp + 32 + lg * 8);
        float4 cd = *(const float4*)(cp + 32 + lg * 8 + 4);
        B8 y0, y1;
        f32x2 pr;
        pr = pkmul((f32x2){ca.x, ca.y}, kop2[0]); y0.u[0] = pk2(pr.x, pr.y);
        pr = pkmul((f32x2){ca.z, ca.w}, kop2[1]); y0.u[1] = pk2(pr.x, pr.y);
        pr = pkmul((f32x2){cb.x, cb.y}, kop2[2]); y0.u[2] = pk2(pr.x, pr.y);
        pr = pkmul((f32x2){cb.z, cb.w}, kop2[3]); y0.u[3] = pk2(pr.x, pr.y);
        pr = pkmul((f32x2){cc.x, cc.y}, kop2[4]); y1.u[0] = pk2(pr.x, pr.y);
        pr = pkmul((f32x2){cc.z, cc.w}, kop2[5]); y1.u[1] = pk2(pr.x, pr.y);
        pr = pkmul((f32x2){cd.x, cd.y}, kop2[6]); y1.u[2] = pk2(pr.x, pr.y);
        pr = pkmul((f32x2){cd.z, cd.w}, kop2[7]); y1.u[3] = pk2(pr.x, pr.y);
        f32x4 kc0 = MFMA(y0.v, aK1[0].v, zz, 0, 0, 0); kc0 = MFMA(y1.v, aK1[1].v, kc0, 0, 0, 0);
        f32x4 kc1 = MFMA(y0.v, aK1[2].v, zz, 0, 0, 0); kc1 = MFMA(y1.v, aK1[3].v, kc1, 0, 0, 0);
        f32x4 kc2 = MFMA(y0.v, aK1[4].v, zz, 0, 0, 0); kc2 = MFMA(y1.v, aK1[5].v, kc2, 0, 0, 0);
        f32x4 kc3 = MFMA(y0.v, aK1[6].v, zz, 0, 0, 0); kc3 = MFMA(y1.v, aK1[7].v, kc3, 0, 0, 0);
        float q0 = qw[p * 68 + lr];
        float q1 = qw[p * 68 + 16 + lr];
        float q2 = qw[p * 68 + 32 + lr];
        float q3 = qw[p * 68 + 48 + lr];
        float d0 = kc0[0] * kc0[0] + kc0[1] * kc0[1] + kc0[2] * kc0[2] + kc0[3] * kc0[3];
        float d1 = kc1[0] * kc1[0] + kc1[1] * kc1[1] + kc1[2] * kc1[2] + kc1[3] * kc1[3];
        float d2 = kc2[0] * kc2[0] + kc2[1] * kc2[1] + kc2[2] * kc2[2] + kc2[3] * kc2[3];
        float d3 = kc3[0] * kc3[0] + kc3[1] * kc3[1] + kc3[2] * kc3[2] + kc3[3] * kc3[3];
        float tp = q0 * d0 + q1 * d1 + q2 * d2 + q3 * d3;
#pragma unroll
        for (int off = 1; off < 64; off <<= 1) tp += __shfl_xor(tp, off, 64);
        if (lane == 0) tshv[wid][p] = tp;
      }

      // ---- grad rows j=0..15: g = [rv; x; t; 1] x [K0 | symA | b]
      {
        B8 rf0, rf1;
        rf0.q = *(const u32x4*)(Xw + p8 * 36 + lg * 4);
        rf1.q = *(const u32x4*)(Xw + p8 * 36 + 16 + lg * 4);
        f32x4 g = MFMA(aG0[0].v, rf0.v, zz, 0, 0, 0);
        g = MFMA(aG0[1].v, rf1.v, g, 0, 0, 0);
        g = MFMA(aG0[2].v, sfG.v, g, 0, 0, 0);
        if (own) {
          float4 gf = {g[0], g[1], g[2], g[3]};
          *(float4*)(gw + p8 * 20 + lg * 4) = gf;
        }
      }
      ldsfence();

      // ---- RK4 update
      float tsum = tshv[wid][p8];
      float4 gv = *(const float4*)(gw + p8 * 20 + lg * 4);
      float kx[4];
      float dvp = 0.f;
#pragma unroll
      for (int r = 0; r < 4; ++r) {
        float d = -((const float*)&gv)[r];
        kx[r] = d; dvp = fmaf(d, d, dvp);
      }
      dvp += __shfl_xor(dvp, 16, 64);
      dvp += __shfl_xor(dvp, 32, 64);
      dvp *= 0.5f;
      float trH = trh_l + tsum + sumA2;
      float dl = -trH;
      float dr = fabsf(dvp - g16);
      float wch = ((st == 0 || st == 3) ? (1.f / 6.f) : (1.f / 3.f)) * h;
#pragma unroll
      for (int r = 0; r < 4; ++r) xac[r] = fmaf(wch, kx[r], xac[r]);
      lacc = fmaf(wch, dl, lacc);
      vacc = fmaf(wch, dvp, vacc);
      racc = fmaf(wch, dr, racc);
      if (st < 3) {
        float anh = ((st == 2) ? 1.f : 0.5f) * h;
#pragma unroll
        for (int r = 0; r < 4; ++r) xin[r] = fmaf(anh, kx[r], x0s[r]);
      } else {
#pragma unroll
        for (int r = 0; r < 4; ++r) { x0s[r] = xac[r]; xin[r] = xac[r]; }
      }
    }
  }

  // ---- outputs
  int pi = pbase + p8;
  if (own && pi < n) {
    float4 xa = {xac[0], xac[1], xac[2], xac[3]};
    *(float4*)(out + (size_t)pi * 16 + lg * 4) = xa;
    if (lg == 0) {
      out[(size_t)n * 16 + pi] = lacc;
      out[(size_t)n * 17 + pi] = vacc;
      out[(size_t)n * 18 + pi] = racc;
    }
  }
}

extern "C" void kernel_launch(void* const* d_in, const int* in_sizes, int n_in,
                              void* d_out, int out_size, void* d_ws, size_t ws_size,
                              hipStream_t stream) {
  const float* xg = (const float*)d_in[0];
  const float* wg = (const float*)d_in[1];
  const float* Ag = (const float*)d_in[2];
  const float* bg = (const float*)d_in[3];
  const float* K0g = (const float*)d_in[4];
  const float* b0g = (const float*)d_in[5];
  const float* K1g = (const float*)d_in[6];
  const float* b1g = (const float*)d_in[7];
  const int* ntg = (const int*)d_in[8];
  float* out = (float*)d_out;
  float* ws = (float*)d_ws;
  int n = in_sizes[0] / 16;

  hipLaunchKernelGGL(otflow_prep, dim3(1), dim3(256), 0, stream, K0g, Ag, ws);
  int nblk = (n + 15) / 16;
  hipLaunchKernelGGL(otflow_main, dim3(nblk), dim3(128), 0, stream,
                     xg, wg, bg, K0g, b0g, K1g, b1g, ntg, ws, out, n);
}

// Round 8
// 349.538 us; speedup vs baseline: 1.9732x; 1.9732x over previous
//
#include <hip/hip_runtime.h>
#include <math.h>

typedef __attribute__((ext_vector_type(8))) short bf16x8;
typedef __attribute__((ext_vector_type(4))) float f32x4;
typedef __attribute__((ext_vector_type(2))) float f32x2;
typedef __attribute__((ext_vector_type(4))) unsigned u32x4;

union B8 { bf16x8 v; unsigned u[4]; u32x4 q; };

__device__ __forceinline__ unsigned pk2(float lo, float hi) {
  unsigned r;
  asm("v_cvt_pk_bf16_f32 %0, %1, %2" : "=v"(r) : "v"(lo), "v"(hi));
  return r;
}
__device__ __forceinline__ f32x2 pkmul(f32x2 a, f32x2 b) {
  f32x2 r;
  asm("v_pk_mul_f32 %0, %1, %2" : "=v"(r) : "v"(a), "v"(b));
  return r;
}
__device__ __forceinline__ float rcpf(float x) { return __builtin_amdgcn_rcpf(x); }
__device__ __forceinline__ void ldsfence() { asm volatile("s_waitcnt lgkmcnt(0)" ::: "memory"); }

#define MFMA __builtin_amdgcn_mfma_f32_16x16x32_bf16

// ---------------- prep: Kopen pack [0..1023], symA [1024..1312], sumA2 [1313], k0sq [1320..1383]
__global__ void otflow_prep(const float* __restrict__ K0g,
                            const float* __restrict__ Ag,
                            float* __restrict__ ws) {
  __shared__ float Als[170];
  int tid = threadIdx.x;
  for (int idx = tid; idx < 1024; idx += 256) {
    int m = idx >> 4, d = idx & 15;
    ws[idx] = K0g[m * 17 + d];
  }
  if (tid < 170) Als[tid] = Ag[tid];
  if (tid < 64) {
    float s = 0.f;
    for (int d = 0; d < 16; ++d) { float v = K0g[tid * 17 + d]; s += v * v; }
    ws[1320 + tid] = s;
  }
  __syncthreads();
  for (int idx = tid; idx < 289; idx += 256) {
    int j = idx / 17, k2 = idx % 17;
    float s = 0.f;
#pragma unroll
    for (int r = 0; r < 10; ++r) s += Als[r * 17 + j] * Als[r * 17 + k2];
    ws[1024 + idx] = s;
  }
  __syncthreads();
  if (tid == 0) {
    float s = 0.f;
    for (int r = 0; r < 10; ++r)
      for (int j = 0; j < 16; ++j) { float v = Als[r * 17 + j]; s += v * v; }
    ws[1313] = s;
  }
}

// ---------------- main: one wave (= one workgroup) per 16 particles (R3 structure)
__global__ __launch_bounds__(64, 2) void otflow_main(
    const float* __restrict__ xg, const float* __restrict__ wg,
    const float* __restrict__ bg, const float* __restrict__ K0g,
    const float* __restrict__ b0g, const float* __restrict__ K1g,
    const float* __restrict__ b1g, const int* __restrict__ ntg,
    const float* __restrict__ ws, float* __restrict__ out, int n) {
  __shared__ __align__(16) float csh[16 * 68];    // S-bounce then c
  __shared__ __align__(16) float qsh[16 * 68];    // q
  __shared__ __align__(16) unsigned Xu[16 * 36];  // packed bf16: u0 -> a -> rv
  __shared__ __align__(16) float tsh[16 * 20];    // t1 per-residue partials
  __shared__ __align__(16) float b0s[64], tcs[64], b1s[64], wss[64], k0qs[64];
  __shared__ __align__(16) float scol[20];

  const int lane = threadIdx.x;
  const int lr = lane & 15;
  const int lg = lane >> 4;

  b0s[lane] = b0g[lane];
  tcs[lane] = K0g[lane * 17 + 16];
  b1s[lane] = b1g[lane];
  wss[lane] = wg[lane];
  k0qs[lane] = ws[1320 + lane];
  if (lane < 17) scol[lane] = ws[1024 + lane * 17 + 16];  // symA[k][16]
  if (lane == 17) scol[17] = bg[16];

  const float sumA2 = ws[1313];

  // ---- const fragments (bf16, VGPR) ----
  B8 aK0[4], aK0L[4];            // opening rows, hi/lo split, k dup over halves
#pragma unroll
  for (int mi = 0; mi < 4; ++mi) {
    B8 th, tl;
#pragma unroll
    for (int jj = 0; jj < 4; ++jj) {
      float e0 = K0g[(mi * 16 + lr) * 17 + (lg & 1) * 8 + jj * 2];
      float e1 = K0g[(mi * 16 + lr) * 17 + (lg & 1) * 8 + jj * 2 + 1];
      unsigned hh = pk2(e0, e1);
      th.u[jj] = hh;
      float l0 = e0 - __uint_as_float(hh << 16);
      float l1 = e1 - __uint_as_float(hh & 0xffff0000u);
      tl.u[jj] = pk2(l0, l1);
    }
    aK0[mi] = th; aK0L[mi] = tl;
  }
  B8 aK1[8];                     // K1 rows (A for feat1; B for KJ)
#pragma unroll
  for (int mi = 0; mi < 4; ++mi)
#pragma unroll
    for (int kb = 0; kb < 2; ++kb) {
      const float* pp = K1g + (mi * 16 + lr) * 64 + kb * 32 + lg * 8;
      float4 q0 = *(const float4*)pp;
      float4 q1 = *(const float4*)(pp + 4);
      B8 t;
      t.u[0] = pk2(q0.x, q0.y); t.u[1] = pk2(q0.z, q0.w);
      t.u[2] = pk2(q1.x, q1.y); t.u[3] = pk2(q1.z, q1.w);
      aK1[mi * 2 + kb] = t;
    }
  B8 aK1T[8];                    // K1^T rows (z1)
#pragma unroll
  for (int mi = 0; mi < 4; ++mi)
#pragma unroll
    for (int kb = 0; kb < 2; ++kb) {
      int ib = kb * 32 + lg * 8;
      int m = mi * 16 + lr;
      B8 tt;
#pragma unroll
      for (int jj = 0; jj < 4; ++jj)
        tt.u[jj] = pk2(K1g[(ib + jj * 2) * 64 + m], K1g[(ib + jj * 2 + 1) * 64 + m]);
      aK1T[mi * 2 + kb] = tt;
    }
  B8 aG0[3];                     // grad rows j=lr: [K0 | symA | b], K=96
  {
    int j = lr;
#pragma unroll
    for (int kb = 0; kb < 3; ++kb) {
      float e[8];
#pragma unroll
      for (int jj = 0; jj < 8; ++jj) {
        float v;
        if (kb < 2) v = K0g[(kb * 32 + lg * 8 + jj) * 17 + j];
        else {
          int kr = lg * 8 + jj;
          v = (kr < 17) ? ws[1024 + kr * 17 + j] : (kr == 17) ? bg[j] : 0.f;
        }
        e[jj] = v;
      }
      B8 t;
      t.u[0] = pk2(e[0], e[1]); t.u[1] = pk2(e[2], e[3]);
      t.u[2] = pk2(e[4], e[5]); t.u[3] = pk2(e[6], e[7]);
      aG0[kb] = t;
    }
  }
  f32x2 kop2[8];                 // Kopen[m][lr] pairs, m = kb*32+lg*8+2j..+1
#pragma unroll
  for (int kb = 0; kb < 2; ++kb)
#pragma unroll
    for (int j = 0; j < 4; ++j) {
      f32x2 t;
      t.x = ws[(kb * 32 + lg * 8 + 2 * j) * 16 + lr];
      t.y = ws[(kb * 32 + lg * 8 + 2 * j + 1) * 16 + lr];
      kop2[kb * 4 + j] = t;
    }

  ldsfence();

  float4 sc4 = *(const float4*)(scol + lg * 4);
  const float sc16 = scol[16], sc17 = scol[17];

  const int nt = *ntg;
  const float h = 1.0f / (float)nt;
  const int p0 = blockIdx.x * 16;
  int pidx = p0 + lr; if (pidx >= n) pidx = n - 1;

  float xin[4], x0s[4], xac[4];
  {
    float4 xi = *(const float4*)(xg + (size_t)pidx * 16 + lg * 4);
    xin[0] = xi.x; xin[1] = xi.y; xin[2] = xi.z; xin[3] = xi.w;
#pragma unroll
    for (int r = 0; r < 4; ++r) { x0s[r] = xin[r]; xac[r] = xin[r]; }
  }
  float lacc = 0.f, vacc = 0.f, racc = 0.f;
  const f32x4 zz = {0.f, 0.f, 0.f, 0.f};

  for (int kstep = 0; kstep < nt; ++kstep) {
    float t0 = (float)kstep * h;
#pragma unroll 1
    for (int st = 0; st < 4; ++st) {
      float tin = t0 + ((st == 0) ? 0.f : (st == 3) ? h : 0.5f * h);

      // ---- S-bounce + frag build (hi/lo exact opening; bf16-hi grad S)
      { float4 xv = {xin[0], xin[1], xin[2], xin[3]};
        *(float4*)(csh + lr * 68 + lg * 4) = xv; }
      ldsfence();
      float4 s0 = *(const float4*)(csh + lr * 68 + (lg & 1) * 8);
      float4 s1 = *(const float4*)(csh + lr * 68 + (lg & 1) * 8 + 4);
      unsigned h0 = pk2(s0.x, s0.y), h1 = pk2(s0.z, s0.w);
      unsigned h2 = pk2(s1.x, s1.y), h3 = pk2(s1.z, s1.w);
      B8 sfO, sfG;
      if (lg < 2) {
        sfO.u[0] = h0; sfO.u[1] = h1; sfO.u[2] = h2; sfO.u[3] = h3;
        sfG.u[0] = h0; sfG.u[1] = h1; sfG.u[2] = h2; sfG.u[3] = h3;
      } else {
        float l0 = s0.x - __uint_as_float(h0 << 16);
        float l1 = s0.y - __uint_as_float(h0 & 0xffff0000u);
        float l2 = s0.z - __uint_as_float(h1 << 16);
        float l3 = s0.w - __uint_as_float(h1 & 0xffff0000u);
        float l4 = s1.x - __uint_as_float(h2 << 16);
        float l5 = s1.y - __uint_as_float(h2 & 0xffff0000u);
        float l6 = s1.z - __uint_as_float(h3 << 16);
        float l7 = s1.w - __uint_as_float(h3 & 0xffff0000u);
        sfO.u[0] = pk2(l0, l1); sfO.u[1] = pk2(l2, l3);
        sfO.u[2] = pk2(l4, l5); sfO.u[3] = pk2(l6, l7);
        if (lg == 2) { sfG.u[0] = pk2(tin, 1.f); sfG.u[1] = 0; sfG.u[2] = 0; sfG.u[3] = 0; }
        else { sfG.u[0] = 0; sfG.u[1] = 0; sfG.u[2] = 0; sfG.u[3] = 0; }
      }

      // ---- opening: o = (K0hi + K0lo) x Shi/lo, + b0 + t*K0[:,16]
      f32x4 o0 = MFMA(aK0[0].v, sfO.v, zz, 0, 0, 0);
      f32x4 o1 = MFMA(aK0[1].v, sfO.v, zz, 0, 0, 0);
      f32x4 o2 = MFMA(aK0[2].v, sfO.v, zz, 0, 0, 0);
      f32x4 o3 = MFMA(aK0[3].v, sfO.v, zz, 0, 0, 0);
      o0 = MFMA(aK0L[0].v, sfO.v, o0, 0, 0, 0);
      o1 = MFMA(aK0L[1].v, sfO.v, o1, 0, 0, 0);
      o2 = MFMA(aK0L[2].v, sfO.v, o2, 0, 0, 0);
      o3 = MFMA(aK0L[3].v, sfO.v, o3, 0, 0, 0);

      float cva[16];
#pragma unroll
      for (int mi = 0; mi < 4; ++mi) {
        f32x4 oa = (mi == 0) ? o0 : (mi == 1) ? o1 : (mi == 2) ? o2 : o3;
        float4 b0v = *(const float4*)(b0s + mi * 16 + lg * 4);
        float4 tcv = *(const float4*)(tcs + mi * 16 + lg * 4);
        float u0v[4];
        float4 cv4;
#pragma unroll
        for (int r = 0; r < 4; ++r) {
          float ov = oa[r] + fmaf(tin, ((const float*)&tcv)[r], ((const float*)&b0v)[r]);
          float e = __expf(-2.f * fabsf(ov));
          float rp = rcpf(1.f + e);
          float c = __builtin_copysignf((1.f - e) * rp, ov);
          cva[mi * 4 + r] = c;
          u0v[r] = fabsf(ov) + __logf(1.f + e);
          ((float*)&cv4)[r] = c;
        }
        *(float4*)(csh + lr * 68 + mi * 16 + lg * 4) = cv4;
        *(uint2*)(Xu + lr * 36 + mi * 8 + lg * 2) =
            make_uint2(pk2(u0v[0], u0v[1]), pk2(u0v[2], u0v[3]));
      }
      ldsfence();

      // ---- feat1 = K1 @ u0 (packed-bf16 direct frag read)
      B8 uf0, uf1;
      uf0.q = *(const u32x4*)(Xu + lr * 36 + lg * 4);
      uf1.q = *(const u32x4*)(Xu + lr * 36 + 16 + lg * 4);
      f32x4 f0 = MFMA(aK1[0].v, uf0.v, zz, 0, 0, 0); f0 = MFMA(aK1[1].v, uf1.v, f0, 0, 0, 0);
      f32x4 f1 = MFMA(aK1[2].v, uf0.v, zz, 0, 0, 0); f1 = MFMA(aK1[3].v, uf1.v, f1, 0, 0, 0);
      f32x4 f2 = MFMA(aK1[4].v, uf0.v, zz, 0, 0, 0); f2 = MFMA(aK1[5].v, uf1.v, f2, 0, 0, 0);
      f32x4 f3 = MFMA(aK1[6].v, uf0.v, zz, 0, 0, 0); f3 = MFMA(aK1[7].v, uf1.v, f3, 0, 0, 0);

#pragma unroll
      for (int mi = 0; mi < 4; ++mi) {
        f32x4 fa = (mi == 0) ? f0 : (mi == 1) ? f1 : (mi == 2) ? f2 : f3;
        float4 b1v = *(const float4*)(b1s + mi * 16 + lg * 4);
        float4 wv = *(const float4*)(wss + mi * 16 + lg * 4);
        float av[4];
        float4 qv4;
#pragma unroll
        for (int r = 0; r < 4; ++r) {
          float fv = fa[r] + ((const float*)&b1v)[r];
          float e = __expf(-2.f * fabsf(fv));
          float rp = rcpf(1.f + e);
          float tf = __builtin_copysignf((1.f - e) * rp, fv);
          float wr = ((const float*)&wv)[r];
          av[r] = tf * wr;
          ((float*)&qv4)[r] = (1.f - tf * tf) * wr;
        }
        *(float4*)(qsh + lr * 68 + mi * 16 + lg * 4) = qv4;
        *(uint2*)(Xu + lr * 36 + mi * 8 + lg * 2) =
            make_uint2(pk2(av[0], av[1]), pk2(av[2], av[3]));
      }
      ldsfence();

      // ---- z1 = K1^T @ a ; rv packed; trh + g16 folds in-register
      B8 af0, af1;
      af0.q = *(const u32x4*)(Xu + lr * 36 + lg * 4);
      af1.q = *(const u32x4*)(Xu + lr * 36 + 16 + lg * 4);
      f32x4 z0 = MFMA(aK1T[0].v, af0.v, zz, 0, 0, 0); z0 = MFMA(aK1T[1].v, af1.v, z0, 0, 0, 0);
      f32x4 z1 = MFMA(aK1T[2].v, af0.v, zz, 0, 0, 0); z1 = MFMA(aK1T[3].v, af1.v, z1, 0, 0, 0);
      f32x4 z2 = MFMA(aK1T[4].v, af0.v, zz, 0, 0, 0); z2 = MFMA(aK1T[5].v, af1.v, z2, 0, 0, 0);
      f32x4 z3 = MFMA(aK1T[6].v, af0.v, zz, 0, 0, 0); z3 = MFMA(aK1T[7].v, af1.v, z3, 0, 0, 0);

      float trh_l = 0.f, g16p = 0.f;
#pragma unroll
      for (int mi = 0; mi < 4; ++mi) {
        f32x4 za = (mi == 0) ? z0 : (mi == 1) ? z1 : (mi == 2) ? z2 : z3;
        float4 wv = *(const float4*)(wss + mi * 16 + lg * 4);
        float4 kq = *(const float4*)(k0qs + mi * 16 + lg * 4);
        float4 tcv = *(const float4*)(tcs + mi * 16 + lg * 4);
        float rv[4];
#pragma unroll
        for (int r = 0; r < 4; ++r) {
          float c = cva[mi * 4 + r];
          float z1v = za[r] + ((const float*)&wv)[r];
          rv[r] = c * z1v;
          trh_l = fmaf((1.f - c * c) * z1v, ((const float*)&kq)[r], trh_l);
          g16p = fmaf(rv[r], ((const float*)&tcv)[r], g16p);
        }
        *(uint2*)(Xu + lr * 36 + mi * 8 + lg * 2) =
            make_uint2(pk2(rv[0], rv[1]), pk2(rv[2], rv[3]));
      }
#pragma unroll
      for (int r = 0; r < 4; ++r) g16p = fmaf(xin[r], ((const float*)&sc4)[r], g16p);
      trh_l += __shfl_xor(trh_l, 16, 64);
      trh_l += __shfl_xor(trh_l, 32, 64);
      g16p += __shfl_xor(g16p, 16, 64);
      g16p += __shfl_xor(g16p, 32, 64);
      float g16 = g16p + fmaf(tin, sc16, sc17);
      ldsfence();

      // ---- KJ per particle: two-stage t1 (R3-verified), pkmul y-build
#pragma unroll 2
      for (int p = 0; p < 16; ++p) {
        const float* cp = csh + p * 68;
        float4 ca = *(const float4*)(cp + lg * 8);
        float4 cb = *(const float4*)(cp + lg * 8 + 4);
        float4 cc = *(const float4*)(cp + 32 + lg * 8);
        float4 cd = *(const float4*)(cp + 32 + lg * 8 + 4);
        B8 y0, y1;
        f32x2 pr;
        pr = pkmul((f32x2){ca.x, ca.y}, kop2[0]); y0.u[0] = pk2(pr.x, pr.y);
        pr = pkmul((f32x2){ca.z, ca.w}, kop2[1]); y0.u[1] = pk2(pr.x, pr.y);
        pr = pkmul((f32x2){cb.x, cb.y}, kop2[2]); y0.u[2] = pk2(pr.x, pr.y);
        pr = pkmul((f32x2){cb.z, cb.w}, kop2[3]); y0.u[3] = pk2(pr.x, pr.y);
        pr = pkmul((f32x2){cc.x, cc.y}, kop2[4]); y1.u[0] = pk2(pr.x, pr.y);
        pr = pkmul((f32x2){cc.z, cc.w}, kop2[5]); y1.u[1] = pk2(pr.x, pr.y);
        pr = pkmul((f32x2){cd.x, cd.y}, kop2[6]); y1.u[2] = pk2(pr.x, pr.y);
        pr = pkmul((f32x2){cd.z, cd.w}, kop2[7]); y1.u[3] = pk2(pr.x, pr.y);
        f32x4 kc0 = MFMA(y0.v, aK1[0].v, zz, 0, 0, 0); kc0 = MFMA(y1.v, aK1[1].v, kc0, 0, 0, 0);
        f32x4 kc1 = MFMA(y0.v, aK1[2].v, zz, 0, 0, 0); kc1 = MFMA(y1.v, aK1[3].v, kc1, 0, 0, 0);
        f32x4 kc2 = MFMA(y0.v, aK1[4].v, zz, 0, 0, 0); kc2 = MFMA(y1.v, aK1[5].v, kc2, 0, 0, 0);
        f32x4 kc3 = MFMA(y0.v, aK1[6].v, zz, 0, 0, 0); kc3 = MFMA(y1.v, aK1[7].v, kc3, 0, 0, 0);
        float q0 = qsh[p * 68 + lr];
        float q1 = qsh[p * 68 + 16 + lr];
        float q2 = qsh[p * 68 + 32 + lr];
        float q3 = qsh[p * 68 + 48 + lr];
        float d0 = kc0[0] * kc0[0] + kc0[1] * kc0[1] + kc0[2] * kc0[2] + kc0[3] * kc0[3];
        float d1 = kc1[0] * kc1[0] + kc1[1] * kc1[1] + kc1[2] * kc1[2] + kc1[3] * kc1[3];
        float d2 = kc2[0] * kc2[0] + kc2[1] * kc2[1] + kc2[2] * kc2[2] + kc2[3] * kc2[3];
        float d3 = kc3[0] * kc3[0] + kc3[1] * kc3[1] + kc3[2] * kc3[2] + kc3[3] * kc3[3];
        float tp = q0 * d0 + q1 * d1 + q2 * d2 + q3 * d3;
        tp += __shfl_xor(tp, 16, 64);
        tp += __shfl_xor(tp, 32, 64);
        if (lg == 0) tsh[p * 20 + lr] = tp;
      }

      // ---- grad rows j=0..15 (in-register C; no LDS bounce)
      B8 rf0, rf1;
      rf0.q = *(const u32x4*)(Xu + lr * 36 + lg * 4);
      rf1.q = *(const u32x4*)(Xu + lr * 36 + 16 + lg * 4);
      f32x4 g0 = MFMA(aG0[0].v, rf0.v, zz, 0, 0, 0);
      g0 = MFMA(aG0[1].v, rf1.v, g0, 0, 0, 0);
      g0 = MFMA(aG0[2].v, sfG.v, g0, 0, 0, 0);
      ldsfence();

      // ---- t1 stage-2 + RK4 update
      float4 tv = *(const float4*)(tsh + lr * 20 + lg * 4);
      float tsum = tv.x + tv.y + tv.z + tv.w;
      tsum += __shfl_xor(tsum, 16, 64);
      tsum += __shfl_xor(tsum, 32, 64);

      float kx[4];
      float dvp = 0.f;
#pragma unroll
      for (int r = 0; r < 4; ++r) { float d = -g0[r]; kx[r] = d; dvp = fmaf(d, d, dvp); }
      dvp += __shfl_xor(dvp, 16, 64);
      dvp += __shfl_xor(dvp, 32, 64);
      dvp *= 0.5f;
      float trH = trh_l + tsum + sumA2;
      float dl = -trH;
      float dr = fabsf(dvp - g16);
      float wch = ((st == 0 || st == 3) ? (1.f / 6.f) : (1.f / 3.f)) * h;
#pragma unroll
      for (int r = 0; r < 4; ++r) xac[r] = fmaf(wch, kx[r], xac[r]);
      lacc = fmaf(wch, dl, lacc);
      vacc = fmaf(wch, dvp, vacc);
      racc = fmaf(wch, dr, racc);
      if (st < 3) {
        float anh = ((st == 2) ? 1.f : 0.5f) * h;
#pragma unroll
        for (int r = 0; r < 4; ++r) xin[r] = fmaf(anh, kx[r], x0s[r]);
      } else {
#pragma unroll
        for (int r = 0; r < 4; ++r) { x0s[r] = xac[r]; xin[r] = xac[r]; }
      }
    }
  }

  // ---- outputs
  if (p0 + lr < n) {
    float4 xa = {xac[0], xac[1], xac[2], xac[3]};
    *(float4*)(out + (size_t)(p0 + lr) * 16 + lg * 4) = xa;
    if (lg == 0) {
      out[(size_t)n * 16 + p0 + lr] = lacc;
      out[(size_t)n * 17 + p0 + lr] = vacc;
      out[(size_t)n * 18 + p0 + lr] = racc;
    }
  }
}

extern "C" void kernel_launch(void* const* d_in, const int* in_sizes, int n_in,
                              void* d_out, int out_size, void* d_ws, size_t ws_size,
                              hipStream_t stream) {
  const float* xg = (const float*)d_in[0];
  const float* wg = (const float*)d_in[1];
  const float* Ag = (const float*)d_in[2];
  const float* bg = (const float*)d_in[3];
  const float* K0g = (const float*)d_in[4];
  const float* b0g = (const float*)d_in[5];
  const float* K1g = (const float*)d_in[6];
  const float* b1g = (const float*)d_in[7];
  const int* ntg = (const int*)d_in[8];
  float* out = (float*)d_out;
  float* ws = (float*)d_ws;
  int n = in_sizes[0] / 16;

  hipLaunchKernelGGL(otflow_prep, dim3(1), dim3(256), 0, stream, K0g, Ag, ws);
  int nblk = (n + 15) / 16;
  hipLaunchKernelGGL(otflow_main, dim3(nblk), dim3(64), 0, stream,
                     xg, wg, bg, K0g, b0g, K1g, b1g, ntg, ws, out, n);
}